// Round 1
// baseline (1927.399 us; speedup 1.0000x reference)
//
#include <hip/hip_runtime.h>

#define NODES_D 64
#define NODES_P 32
#define NODES_Q 32

__device__ __forceinline__ float softplus_f(float x) {
    // stable: max(x,0) + log1p(exp(-|x|))
    return fmaxf(x, 0.0f) + log1pf(expf(-fabsf(x)));
}

// ---------------- edge aggregation: nbr_sum += intensity[src], deg[dst] += 1
__global__ void edge_kernel(const float* __restrict__ intensity,
                            const int* __restrict__ esrc,
                            const int* __restrict__ edst,
                            float* __restrict__ nbr_sum,
                            float* __restrict__ deg,
                            int nwork /* = E*8 */) {
    int t0 = blockIdx.x * blockDim.x + threadIdx.x;
    int stride = gridDim.x * blockDim.x;
    for (int t = t0; t < nwork; t += stride) {
        int e = t >> 3;
        int part = t & 7;
        int s = esrc[e];
        int d = edst[e];
        float4 v = ((const float4*)intensity)[s * 8 + part];
        float* dst = nbr_sum + d * 32 + part * 4;
        atomicAdd(dst + 0, v.x);
        atomicAdd(dst + 1, v.y);
        atomicAdd(dst + 2, v.z);
        atomicAdd(dst + 3, v.w);
        if (part == 0) atomicAdd(deg + d, 1.0f);
    }
}

// ---------------- fused node kernel: one wave (64 lanes) per node
__global__ __launch_bounds__(256) void node_kernel(
    const float* __restrict__ u,
    const float* __restrict__ intensity,
    const float* __restrict__ Wf, const float* __restrict__ bf,
    const float* __restrict__ Wg, const float* __restrict__ bg,
    const float* __restrict__ Wz, const float* __restrict__ bz,
    const float* __restrict__ WA, const float* __restrict__ bA,
    const float* __restrict__ nbr_sum, const float* __restrict__ deg,
    float* __restrict__ out, int N) {
    // weights transposed into LDS: s[k*64+i] = W[i][k]
    __shared__ float sWf[64 * 64];
    __shared__ float sWg[64 * 64];
    __shared__ float sW3[64 * 64];  // rows 0..31 = Wz, rows 32..63 = WA
    __shared__ float sb[3 * 64];

    int tid = threadIdx.x;
    for (int idx = tid; idx < 64 * 64; idx += blockDim.x) {
        int i = idx & 63;      // row (output feature)
        int k = idx >> 6;      // col (input feature)
        // writes: consecutive lanes -> consecutive i -> consecutive words (no conflict)
        sWf[k * 64 + i] = Wf[i * 64 + k];
        sWg[k * 64 + i] = Wg[i * 64 + k];
        sW3[k * 64 + i] = (i < 32) ? Wz[i * 64 + k] : WA[(i - 32) * 64 + k];
    }
    if (tid < 64) {
        sb[tid] = bf[tid];
        sb[64 + tid] = bg[tid];
        sb[128 + tid] = (tid < 32) ? bz[tid] : bA[tid - 32];
    }
    __syncthreads();

    int lane = tid & 63;
    int wave = tid >> 6;
    int wavesPerBlock = blockDim.x >> 6;
    int gwave = blockIdx.x * wavesPerBlock + wave;
    int waveStride = gridDim.x * wavesPerBlock;

    for (int n = gwave; n < N; n += waveStride) {
        float uval = u[n * 64 + lane];
        float dg = deg[n];
        float xval;
        if (lane < 32) {
            xval = intensity[n * 32 + lane];
        } else {
            float s = nbr_sum[n * 32 + (lane - 32)];
            xval = (dg > 0.0f) ? s / fmaxf(dg, 1.0f) : 0.0f;
        }

        float fAcc = sb[lane];
        float gAcc = sb[64 + lane];
        float zAcc = sb[128 + lane];

        #pragma unroll
        for (int k = 0; k < 64; ++k) {
            float uk = __shfl(uval, k);
            float xk = __shfl(xval, k);
            float w3in = (lane < 32) ? uk : xk;
            fAcc = fmaf(sWf[k * 64 + lane], uk, fAcc);
            gAcc = fmaf(sWg[k * 64 + lane], uk, gAcc);
            zAcc = fmaf(sW3[k * 64 + lane], w3in, zAcc);
        }

        float Fu = softplus_f(fAcc);
        float Gu = softplus_f(gAcc);
        float zv = (lane < 32) ? tanhf(zAcc) : fmaxf(zAcc, 0.0f);
        float du = -Fu * uval + Gu * zv;

        // projection over first 32 features
        float a = (lane < 32) ? du * uval : 0.0f;
        float b = (lane < 32) ? uval * uval : 0.0f;
        #pragma unroll
        for (int off = 32; off; off >>= 1) {
            a += __shfl_xor(a, off);
            b += __shfl_xor(b, off);
        }
        float res = (lane < 32) ? (du - (a / b) * uval) : du;
        out[n * 64 + lane] = res;
    }
}

extern "C" void kernel_launch(void* const* d_in, const int* in_sizes, int n_in,
                              void* d_out, int out_size, void* d_ws, size_t ws_size,
                              hipStream_t stream) {
    const float* u         = (const float*)d_in[0];
    const float* intensity = (const float*)d_in[1];
    const int*   esrc      = (const int*)d_in[2];
    const int*   edst      = (const int*)d_in[3];
    const float* Wf        = (const float*)d_in[4];
    const float* bf        = (const float*)d_in[5];
    const float* Wg        = (const float*)d_in[6];
    const float* bg        = (const float*)d_in[7];
    const float* Wz        = (const float*)d_in[8];
    const float* bz        = (const float*)d_in[9];
    const float* WA        = (const float*)d_in[10];
    const float* bA        = (const float*)d_in[11];

    int N = in_sizes[0] / 64;
    int E = in_sizes[2];

    float* nbr_sum = (float*)d_ws;          // N*32 floats
    float* deg     = nbr_sum + (size_t)N * 32;  // N floats

    hipMemsetAsync(d_ws, 0, ((size_t)N * 32 + N) * sizeof(float), stream);

    int nwork = E * 8;
    edge_kernel<<<8192, 256, 0, stream>>>(intensity, esrc, edst, nbr_sum, deg, nwork);

    node_kernel<<<2048, 256, 0, stream>>>(u, intensity, Wf, bf, Wg, bg, Wz, bz,
                                          WA, bA, nbr_sum, deg, (float*)d_out, N);
}

// Round 2
// 632.093 us; speedup vs baseline: 3.0492x; 3.0492x over previous
//
#include <hip/hip_runtime.h>

// N=100000 nodes, D=64, P=Q=32, E=3200000 edges.

__device__ __forceinline__ float softplus_f(float x) {
    return fmaxf(x, 0.0f) + log1pf(expf(-fabsf(x)));
}

__device__ __forceinline__ float bcastf(float v, int k) {
    return __uint_as_float(__builtin_amdgcn_readlane(__float_as_uint(v), k));
}

// ---- 1. histogram of in-degrees (int atomics, 400KB array, L2-resident)
__global__ void hist_kernel(const int* __restrict__ edst, int* __restrict__ cnt, int E4) {
    int t0 = blockIdx.x * blockDim.x + threadIdx.x;
    int stride = gridDim.x * blockDim.x;
    for (int t = t0; t < E4; t += stride) {
        int4 d = ((const int4*)edst)[t];
        atomicAdd(&cnt[d.x], 1);
        atomicAdd(&cnt[d.y], 1);
        atomicAdd(&cnt[d.z], 1);
        atomicAdd(&cnt[d.w], 1);
    }
}

// ---- 2a. per-block partial sums
__global__ void scan_reduce(const int* __restrict__ cnt, int* __restrict__ bsum, int N) {
    int idx = blockIdx.x * 1024 + threadIdx.x;
    int v = (idx < N) ? cnt[idx] : 0;
    #pragma unroll
    for (int off = 32; off; off >>= 1) v += __shfl_xor(v, off);
    __shared__ int wtot[16];
    int lane = threadIdx.x & 63, wave = threadIdx.x >> 6;
    if (lane == 0) wtot[wave] = v;
    __syncthreads();
    if (threadIdx.x == 0) {
        int s = 0;
        #pragma unroll
        for (int i = 0; i < 16; ++i) s += wtot[i];
        bsum[blockIdx.x] = s;
    }
}

// ---- 2b. exclusive scan of block sums (nb <= 128, one block)
__global__ void scan_top(int* __restrict__ bsum, int nb) {
    int t = threadIdx.x;
    int v = (t < nb) ? bsum[t] : 0;
    int lane = t & 63, wave = t >> 6;
    int incl = v;
    #pragma unroll
    for (int off = 1; off < 64; off <<= 1) {
        int w = __shfl_up(incl, off);
        if (lane >= off) incl += w;
    }
    __shared__ int wt[2];
    if (lane == 63) wt[wave] = incl;
    __syncthreads();
    int excl = incl - v + ((wave == 1) ? wt[0] : 0);
    if (t < nb) bsum[t] = excl;
}

// ---- 2c. final exclusive scan -> offs
__global__ void scan_final(const int* __restrict__ cnt, const int* __restrict__ bsum,
                           int* __restrict__ offs, int N) {
    int t = threadIdx.x;
    int idx = blockIdx.x * 1024 + t;
    int lane = t & 63, wave = t >> 6;
    int v = (idx < N) ? cnt[idx] : 0;
    int incl = v;
    #pragma unroll
    for (int off = 1; off < 64; off <<= 1) {
        int w = __shfl_up(incl, off);
        if (lane >= off) incl += w;
    }
    __shared__ int wtot[16];
    if (lane == 63) wtot[wave] = incl;
    __syncthreads();
    int woff = 0;
    for (int i = 0; i < wave; ++i) woff += wtot[i];
    if (idx < N) offs[idx] = bsum[blockIdx.x] + woff + incl - v;
}

// ---- 3. scatter edges into CSR (offs becomes end-pointers)
__global__ void scatter_kernel(const int* __restrict__ esrc, const int* __restrict__ edst,
                               int* __restrict__ offs, int* __restrict__ csr, int E4) {
    int t0 = blockIdx.x * blockDim.x + threadIdx.x;
    int stride = gridDim.x * blockDim.x;
    for (int t = t0; t < E4; t += stride) {
        int4 s = ((const int4*)esrc)[t];
        int4 d = ((const int4*)edst)[t];
        csr[atomicAdd(&offs[d.x], 1)] = s.x;
        csr[atomicAdd(&offs[d.y], 1)] = s.y;
        csr[atomicAdd(&offs[d.z], 1)] = s.z;
        csr[atomicAdd(&offs[d.w], 1)] = s.w;
    }
}

// ---- 4. gather: one wave per node, 4 edges per iteration (float2 per lane)
__global__ __launch_bounds__(256) void gather_kernel(
    const float* __restrict__ intensity, const int* __restrict__ csr,
    const int* __restrict__ offs_end, const int* __restrict__ cnt,
    float* __restrict__ nbr_mean, int N) {
    int lane = threadIdx.x & 63;
    int wave = threadIdx.x >> 6;
    int gwave = blockIdx.x * 4 + wave;
    int wstride = gridDim.x * 4;
    int gid = lane >> 4;       // 4 groups of 16 lanes
    int fl = lane & 15;        // feature pair index
    for (int n = gwave; n < N; n += wstride) {
        int deg = cnt[n];
        int end = offs_end[n];
        int start = end - deg;
        float ax = 0.0f, ay = 0.0f;
        for (int j = gid; j < deg; j += 4) {
            int s = csr[start + j];   // same addr across the 16-lane group -> broadcast
            float2 v = ((const float2*)intensity)[s * 16 + fl];
            ax += v.x; ay += v.y;
        }
        ax += __shfl_xor(ax, 16); ay += __shfl_xor(ay, 16);
        ax += __shfl_xor(ax, 32); ay += __shfl_xor(ay, 32);
        if (lane < 16) {
            float inv = (deg > 0) ? 1.0f / (float)deg : 0.0f;
            float2 r; r.x = ax * inv; r.y = ay * inv;
            ((float2*)nbr_mean)[(size_t)n * 16 + fl] = r;
        }
    }
}

// ---- 5. fused node kernel: weights in registers, readlane broadcast
__global__ __launch_bounds__(256, 2) void node_kernel(
    const float* __restrict__ u, const float* __restrict__ intensity,
    const float* __restrict__ nbr_mean,
    const float* __restrict__ Wf, const float* __restrict__ bf,
    const float* __restrict__ Wg, const float* __restrict__ bg,
    const float* __restrict__ Wz, const float* __restrict__ bz,
    const float* __restrict__ WA, const float* __restrict__ bA,
    float* __restrict__ out, int N) {
    __shared__ float sWf[64 * 65];
    __shared__ float sWg[64 * 65];
    __shared__ float sW3[64 * 65];
    int tid = threadIdx.x;
    for (int idx = tid; idx < 4096; idx += 256) {
        int i = idx >> 6, k = idx & 63;         // consecutive tid -> consecutive k: coalesced reads
        sWf[i * 65 + k] = Wf[idx];
        sWg[i * 65 + k] = Wg[idx];
        sW3[i * 65 + k] = (i < 32) ? Wz[i * 64 + k] : WA[(i - 32) * 64 + k];
    }
    __syncthreads();

    int lane = tid & 63;
    int wave = tid >> 6;

    // register-resident weight rows (pad-65 -> conflict-free stride reads)
    float wf[64], wg[64], w3[64];
    #pragma unroll
    for (int k = 0; k < 64; ++k) {
        wf[k] = sWf[lane * 65 + k];
        wg[k] = sWg[lane * 65 + k];
        w3[k] = sW3[lane * 65 + k];
    }
    float fb = bf[lane];
    float gb = bg[lane];
    float zb = (lane < 32) ? bz[lane] : bA[lane - 32];

    int gwave = blockIdx.x * 4 + wave;
    int wstride = gridDim.x * 4;
    for (int n = gwave; n < N; n += wstride) {
        float uval = u[(size_t)n * 64 + lane];
        float xval = (lane < 32) ? intensity[(size_t)n * 32 + lane]
                                 : nbr_mean[(size_t)n * 32 + (lane - 32)];
        float fA = fb, gA = gb, zA = zb;
        #pragma unroll
        for (int k = 0; k < 64; ++k) {
            float uk = bcastf(uval, k);
            float xk = bcastf(xval, k);
            float in3 = (lane < 32) ? uk : xk;
            fA = fmaf(wf[k], uk, fA);
            gA = fmaf(wg[k], uk, gA);
            zA = fmaf(w3[k], in3, zA);
        }
        float Fu = softplus_f(fA);
        float Gu = softplus_f(gA);
        float zv = (lane < 32) ? tanhf(zA) : fmaxf(zA, 0.0f);
        float du = -Fu * uval + Gu * zv;

        float a = (lane < 32) ? du * uval : 0.0f;
        float b = (lane < 32) ? uval * uval : 0.0f;
        #pragma unroll
        for (int off = 32; off; off >>= 1) {
            a += __shfl_xor(a, off);
            b += __shfl_xor(b, off);
        }
        out[(size_t)n * 64 + lane] = (lane < 32) ? (du - (a / b) * uval) : du;
    }
}

extern "C" void kernel_launch(void* const* d_in, const int* in_sizes, int n_in,
                              void* d_out, int out_size, void* d_ws, size_t ws_size,
                              hipStream_t stream) {
    const float* u         = (const float*)d_in[0];
    const float* intensity = (const float*)d_in[1];
    const int*   esrc      = (const int*)d_in[2];
    const int*   edst      = (const int*)d_in[3];
    const float* Wf        = (const float*)d_in[4];
    const float* bf        = (const float*)d_in[5];
    const float* Wg        = (const float*)d_in[6];
    const float* bg        = (const float*)d_in[7];
    const float* Wz        = (const float*)d_in[8];
    const float* bz        = (const float*)d_in[9];
    const float* WA        = (const float*)d_in[10];
    const float* bA        = (const float*)d_in[11];

    int N = in_sizes[0] / 64;
    int E = in_sizes[2];
    int E4 = E / 4;
    int nb = (N + 1023) / 1024;

    int* cnt  = (int*)d_ws;            // N
    int* offs = cnt + N;               // N
    int* bsum = offs + N;              // 128
    int* csr  = bsum + 128;            // E
    float* nbr_mean = (float*)(csr + E);  // N*32 floats

    hipMemsetAsync(cnt, 0, (size_t)N * sizeof(int), stream);
    hist_kernel<<<1024, 256, 0, stream>>>(edst, cnt, E4);
    scan_reduce<<<nb, 1024, 0, stream>>>(cnt, bsum, N);
    scan_top<<<1, 128, 0, stream>>>(bsum, nb);
    scan_final<<<nb, 1024, 0, stream>>>(cnt, bsum, offs, N);
    scatter_kernel<<<1024, 256, 0, stream>>>(esrc, edst, offs, csr, E4);
    gather_kernel<<<2048, 256, 0, stream>>>(intensity, csr, offs, cnt, nbr_mean, N);
    node_kernel<<<1024, 256, 0, stream>>>(u, intensity, nbr_mean, Wf, bf, Wg, bg,
                                          Wz, bz, WA, bA, (float*)d_out, N);
}